// Round 6
// baseline (463.518 us; speedup 1.0000x reference)
//
#include <hip/hip_runtime.h>
#include <math.h>

typedef __attribute__((ext_vector_type(8))) short short8;
typedef __attribute__((ext_vector_type(4))) float f32x4;

__device__ __forceinline__ unsigned short bf16_bits(float f) {
  unsigned u = __float_as_uint(f);
  u += 0x7fffu + ((u >> 16) & 1u);
  return (unsigned short)(u >> 16);
}

// ---------------------------------------------------------------- K0b: prep
// Fold BN scales into weights/biases; W2 -> bf16 (scaled by s2).
__global__ __launch_bounds__(256) void k0b_prep(
    const float* __restrict__ W1, const float* __restrict__ b1, const float* __restrict__ g1,
    const float* __restrict__ be1, const float* __restrict__ m1, const float* __restrict__ v1,
    const float* __restrict__ W2, const float* __restrict__ b2, const float* __restrict__ g2,
    const float* __restrict__ be2, const float* __restrict__ m2, const float* __restrict__ v2,
    unsigned short* __restrict__ W2b, float4* __restrict__ xyzb,
    float* __restrict__ bias2c, float* __restrict__ s1arr) {
  const int so = blockIdx.x;      // s*256 + o
  const int j  = threadIdx.x;
  const float s2 = rsqrtf(v2[so] + 1e-5f) * g2[so];
  W2b[(size_t)so * 256 + j] = bf16_bits(W2[(size_t)so * 256 + j] * s2);
  if (j == 0) {
    const float s1 = rsqrtf(v1[so] + 1e-5f) * g1[so];
    const float* wr = W1 + (size_t)so * 515;
    xyzb[so] = make_float4(wr[0] * s1, wr[1] * s1, wr[2] * s1,
                           (b1[so] - m1[so]) * s1 + be1[so]);
    bias2c[so] = (b2[so] - m2[so]) * s2 + be2[so];
    s1arr[so] = s1;
  }
}

// ------------------------------------------------------------ K0: neighbors
// One wave per (b,m): ascending-n scan with ballot/popcount reproduces the
// reference's stable-argsort "first 16 masked indices" exactly.
__global__ __launch_bounds__(256) void k0_neighbors(
    const float* __restrict__ xyz, const float* __restrict__ rot,
    int* __restrict__ idx_arr, float4* __restrict__ gxyz4) {
  const int wid = threadIdx.x >> 6, lane = threadIdx.x & 63;
  const int gw = blockIdx.x * 4 + wid;
  const int b = gw >> 10, m = gw & 1023;
  const float* pm = xyz + (size_t)(b * 1024 + m) * 3;
  const float cx = pm[0], cy = pm[1], cz = pm[2];
  const float* pr = rot + (size_t)(b * 1024 + m) * 9;
  float R[9];
#pragma unroll
  for (int i = 0; i < 9; ++i) R[i] = pr[i];
  const float radf[4] = {0.0125f, 0.025f, 0.0375f, 0.05f};
  const float rad2[4] = {(float)(0.0125 * 0.0125), (float)(0.025 * 0.025),
                         (float)(0.0375 * 0.0375), (float)(0.05 * 0.05)};
  int cnt[4] = {0, 0, 0, 0};
  int firstn[4] = {0, 0, 0, 0};
  float f0x[4] = {0, 0, 0, 0}, f0y[4] = {0, 0, 0, 0}, f0z[4] = {0, 0, 0, 0};
  for (int n0 = 0; n0 < 1024; n0 += 64) {
    const int n = n0 + lane;
    const float* pn = xyz + (size_t)(b * 1024 + n) * 3;
    const float dx = pn[0] - cx, dy = pn[1] - cy, dz = pn[2] - cz;
    const float l0 = dx * R[0] + dy * R[3] + dz * R[6];
    const float l1 = dx * R[1] + dy * R[4] + dz * R[7];
    const float l2 = dx * R[2] + dy * R[5] + dz * R[8];
    const float d2 = l1 * l1 + l2 * l2;
    const bool hok = (l0 > -0.02f) && (l0 < 0.04f);
#pragma unroll
    for (int s = 0; s < 4; ++s) {
      if (cnt[s] >= 16) continue;                       // wave-uniform
      const bool p = hok && (d2 < rad2[s]);
      const unsigned long long bal = __ballot(p);
      if (bal == 0ull) continue;                        // wave-uniform
      if (cnt[s] == 0) {
        const int src = __builtin_ctzll(bal);
        firstn[s] = n0 + src;
        f0x[s] = __shfl(l0, src);
        f0y[s] = __shfl(l1, src);
        f0z[s] = __shfl(l2, src);
      }
      const int rank = __popcll(bal & ((1ull << lane) - 1ull));
      const int slot = cnt[s] + rank;
      if (p && slot < 16) {
        const size_t base = ((size_t)((s * 2 + b) * 1024 + m)) * 16 + slot;
        idx_arr[base] = n;
        gxyz4[base] = make_float4(l0 / radf[s], l1 / radf[s], l2 / radf[s], 0.f);
      }
      cnt[s] = min(cnt[s] + (int)__popcll(bal), 16);
    }
  }
#pragma unroll
  for (int s = 0; s < 4; ++s) {
    if (lane < 16 && lane >= cnt[s]) {
      const size_t base = ((size_t)((s * 2 + b) * 1024 + m)) * 16 + lane;
      idx_arr[base] = firstn[s];
      gxyz4[base] = make_float4(f0x[s] / radf[s], f0y[s] / radf[s], f0z[s] / radf[s], 0.f);
    }
  }
}

// ---------------------------------------------------------------- K1: F1 GEMM
// F1[s][b][n][o] = sum_c feats[b][c][n] * W1[s][o][3+c] * s1[s][o]
__global__ __launch_bounds__(256) void k1_f1(
    const float* __restrict__ feats, const float* __restrict__ W1,
    const float* __restrict__ s1arr, float* __restrict__ F1) {
  __shared__ float At[16][68];
  __shared__ float Bt[16][68];
  const int bid = blockIdx.x;
  const int ogt = bid & 15, nt = (bid >> 4) & 15, b = bid >> 8;
  const int og0 = ogt * 64, n0 = nt * 64;
  const int tx = threadIdx.x & 15, ty = threadIdx.x >> 4;
  float acc[4][4] = {};
  for (int c0 = 0; c0 < 512; c0 += 16) {
#pragma unroll
    for (int it = 0; it < 4; ++it) {
      const int t = threadIdx.x + it * 256;
      const int cc = t >> 6, nn = t & 63;
      At[cc][nn] = feats[((size_t)(b * 512 + c0 + cc)) * 1024 + n0 + nn];
      const int og = og0 + nn;
      Bt[cc][nn] = W1[(size_t)og * 515 + 3 + c0 + cc] * s1arr[og];
    }
    __syncthreads();
#pragma unroll
    for (int cc = 0; cc < 16; ++cc) {
      const float4 a = *(const float4*)&At[cc][ty * 4];
      const float4 bv = *(const float4*)&Bt[cc][tx * 4];
      const float av[4] = {a.x, a.y, a.z, a.w};
      const float bw[4] = {bv.x, bv.y, bv.z, bv.w};
#pragma unroll
      for (int i = 0; i < 4; ++i)
#pragma unroll
        for (int j = 0; j < 4; ++j) acc[i][j] = fmaf(av[i], bw[j], acc[i][j]);
    }
    __syncthreads();
  }
  const int s = og0 >> 8;
  const int obase = (og0 & 255) + tx * 4;
#pragma unroll
  for (int i = 0; i < 4; ++i) {
    const int n = n0 + ty * 4 + i;
    float4 w;
    w.x = acc[i][0]; w.y = acc[i][1]; w.z = acc[i][2]; w.w = acc[i][3];
    *(float4*)&F1[(((size_t)(s * 2 + b)) * 1024 + n) * 256 + obase] = w;
  }
}

// ------------------------------------------------- K2: finalize L1 + L2 MFMA + max
// One wave per (s,b,m). A = Y1t[16 samp][256 j] built in-register (row = lane&15),
// B = W2b K-major. Same k-map on both operands => layout-permutation safe.
__global__ __launch_bounds__(256) void k2_layer2(
    const int* __restrict__ idx_arr, const float4* __restrict__ gxyz4,
    const float* __restrict__ F1, const unsigned short* __restrict__ W2b,
    const float4* __restrict__ xyzb, const float* __restrict__ bias2c,
    float* __restrict__ cat) {
  const int wid = threadIdx.x >> 6, lane = threadIdx.x & 63;
  const int bid = blockIdx.x;
  const int mg = bid & 255, b = (bid >> 8) & 1, s = bid >> 9;
  const int m = mg * 4 + wid;
  const int r = lane & 15, hi = lane >> 4;
  const size_t sb = (size_t)((s * 2 + b) * 1024 + m) * 16 + r;
  const int n = idx_arr[sb];
  const float4 g = gxyz4[sb];
  const float* __restrict__ f1row = F1 + ((size_t)((s * 2 + b) * 1024) + n) * 256;
  const unsigned short* __restrict__ w2s = W2b + (size_t)s * 65536;
  const float4* __restrict__ xbs = xyzb + s * 256;
  f32x4 acc[16];
#pragma unroll
  for (int t = 0; t < 16; ++t) { acc[t][0] = 0.f; acc[t][1] = 0.f; acc[t][2] = 0.f; acc[t][3] = 0.f; }
#pragma unroll
  for (int ks = 0; ks < 8; ++ks) {
    const int j0 = ks * 32 + hi * 8;
    const float4 fa = *(const float4*)(f1row + j0);
    const float4 fb = *(const float4*)(f1row + j0 + 4);
    const float fv[8] = {fa.x, fa.y, fa.z, fa.w, fb.x, fb.y, fb.z, fb.w};
    short8 af;
#pragma unroll
    for (int i = 0; i < 8; ++i) {
      const float4 xb = xbs[j0 + i];
      float v = fv[i] + xb.w;
      v = fmaf(g.x, xb.x, v);
      v = fmaf(g.y, xb.y, v);
      v = fmaf(g.z, xb.z, v);
      v = fmaxf(v, 0.f);
      af[i] = (short)bf16_bits(v);
    }
#pragma unroll
    for (int t = 0; t < 16; ++t) {
      const short8 bfr = *(const short8*)(w2s + ((size_t)(t * 16 + r)) * 256 + j0);
      acc[t] = __builtin_amdgcn_mfma_f32_16x16x32_bf16(af, bfr, acc[t], 0, 0, 0);
    }
  }
  float* __restrict__ catrow = cat + ((size_t)(b * 1024 + m)) * 1024 + s * 256;
#pragma unroll
  for (int t = 0; t < 16; ++t) {
    const float bc = bias2c[s * 256 + t * 16 + r];
    float mv = fmaxf(acc[t][0] + bc, 0.f);
    mv = fmaxf(mv, fmaxf(acc[t][1] + bc, 0.f));
    mv = fmaxf(mv, fmaxf(acc[t][2] + bc, 0.f));
    mv = fmaxf(mv, fmaxf(acc[t][3] + bc, 0.f));
    mv = fmaxf(mv, __shfl_xor(mv, 16));
    mv = fmaxf(mv, __shfl_xor(mv, 32));
    if (hi == 0) catrow[t * 16 + r] = mv;
  }
}

// ------------------------------------------------------------ K3a: trans GEMM
__global__ __launch_bounds__(256) void k3_trans(
    const float* __restrict__ feats, const float* __restrict__ W,
    const float* __restrict__ bias, float* __restrict__ outp) {
  __shared__ float At[16][68];
  __shared__ float Bt[16][68];
  const int bid = blockIdx.x;
  const int ot = bid & 3, nt = (bid >> 2) & 15, b = bid >> 6;
  const int og0 = ot * 64, m0 = nt * 64;
  const int tx = threadIdx.x & 15, ty = threadIdx.x >> 4;
  float acc[4][4] = {};
  for (int c0 = 0; c0 < 512; c0 += 16) {
#pragma unroll
    for (int it = 0; it < 4; ++it) {
      const int t = threadIdx.x + it * 256;
      const int cc = t >> 6, nn = t & 63;
      At[cc][nn] = feats[((size_t)(b * 512 + c0 + cc)) * 1024 + m0 + nn];
      Bt[cc][nn] = W[(size_t)(og0 + nn) * 512 + c0 + cc];
    }
    __syncthreads();
#pragma unroll
    for (int cc = 0; cc < 16; ++cc) {
      const float4 a = *(const float4*)&At[cc][ty * 4];
      const float4 bv = *(const float4*)&Bt[cc][tx * 4];
      const float av[4] = {a.x, a.y, a.z, a.w};
      const float bw[4] = {bv.x, bv.y, bv.z, bv.w};
#pragma unroll
      for (int i = 0; i < 4; ++i)
#pragma unroll
        for (int j = 0; j < 4; ++j) acc[i][j] = fmaf(av[i], bw[j], acc[i][j]);
    }
    __syncthreads();
  }
#pragma unroll
  for (int j = 0; j < 4; ++j) {
    const int og = og0 + tx * 4 + j;
    const float bb = bias[og];
#pragma unroll
    for (int i = 0; i < 4; ++i)
      outp[((size_t)(b * 256 + og)) * 1024 + m0 + ty * 4 + i] = acc[i][j] + bb;
  }
}

// ------------------------------------------------------------- K3b: fuse GEMM
__global__ __launch_bounds__(256) void k3_fuse(
    const float* __restrict__ cat, const float* __restrict__ W,
    const float* __restrict__ bias, float* __restrict__ outp) {
  __shared__ float At[16][68];
  __shared__ float Bt[16][68];
  const int bid = blockIdx.x;
  const int ot = bid & 3, nt = (bid >> 2) & 15, b = bid >> 6;
  const int og0 = ot * 64, m0 = nt * 64;
  const int tx = threadIdx.x & 15, ty = threadIdx.x >> 4;
  float acc[4][4] = {};
  for (int c0 = 0; c0 < 1024; c0 += 16) {
#pragma unroll
    for (int it = 0; it < 4; ++it) {
      const int t = threadIdx.x + it * 256;
      { const int mm = t >> 4, cj = t & 15;           // transpose-stage A from cat[b][m][c]
        At[cj][mm] = cat[((size_t)(b * 1024 + m0 + mm)) * 1024 + c0 + cj]; }
      { const int cc = t >> 6, nn = t & 63;
        Bt[cc][nn] = W[(size_t)(og0 + nn) * 1024 + c0 + cc]; }
    }
    __syncthreads();
#pragma unroll
    for (int cc = 0; cc < 16; ++cc) {
      const float4 a = *(const float4*)&At[cc][ty * 4];
      const float4 bv = *(const float4*)&Bt[cc][tx * 4];
      const float av[4] = {a.x, a.y, a.z, a.w};
      const float bw[4] = {bv.x, bv.y, bv.z, bv.w};
#pragma unroll
      for (int i = 0; i < 4; ++i)
#pragma unroll
        for (int j = 0; j < 4; ++j) acc[i][j] = fmaf(av[i], bw[j], acc[i][j]);
    }
    __syncthreads();
  }
#pragma unroll
  for (int j = 0; j < 4; ++j) {
    const int og = og0 + tx * 4 + j;
    const float bb = bias[og];
#pragma unroll
    for (int i = 0; i < 4; ++i)
      outp[((size_t)(b * 256 + og)) * 1024 + m0 + ty * 4 + i] = acc[i][j] + bb;
  }
}

// --------------------------------------------- K3c: gate GEMM + final combine
__global__ __launch_bounds__(256) void k3_gate(
    const float* __restrict__ seedt, const float* __restrict__ W,
    const float* __restrict__ bias, const float* __restrict__ fused,
    float* __restrict__ outp) {
  __shared__ float At[16][68];
  __shared__ float Bt[16][68];
  const int bid = blockIdx.x;
  const int ot = bid & 3, nt = (bid >> 2) & 15, b = bid >> 6;
  const int og0 = ot * 64, m0 = nt * 64;
  const int tx = threadIdx.x & 15, ty = threadIdx.x >> 4;
  float acc[4][4] = {};
  for (int c0 = 0; c0 < 256; c0 += 16) {
#pragma unroll
    for (int it = 0; it < 4; ++it) {
      const int t = threadIdx.x + it * 256;
      const int cc = t >> 6, nn = t & 63;
      At[cc][nn] = seedt[((size_t)(b * 256 + c0 + cc)) * 1024 + m0 + nn];
      Bt[cc][nn] = W[(size_t)(og0 + nn) * 256 + c0 + cc];
    }
    __syncthreads();
#pragma unroll
    for (int cc = 0; cc < 16; ++cc) {
      const float4 a = *(const float4*)&At[cc][ty * 4];
      const float4 bv = *(const float4*)&Bt[cc][tx * 4];
      const float av[4] = {a.x, a.y, a.z, a.w};
      const float bw[4] = {bv.x, bv.y, bv.z, bv.w};
#pragma unroll
      for (int i = 0; i < 4; ++i)
#pragma unroll
        for (int j = 0; j < 4; ++j) acc[i][j] = fmaf(av[i], bw[j], acc[i][j]);
    }
    __syncthreads();
  }
#pragma unroll
  for (int j = 0; j < 4; ++j) {
    const int og = og0 + tx * 4 + j;
    const float gb = bias[og];
#pragma unroll
    for (int i = 0; i < 4; ++i) {
      const size_t oidx = ((size_t)(b * 256 + og)) * 1024 + m0 + ty * 4 + i;
      const float a = acc[i][j] + gb;
      const float gv = 1.f / (1.f + expf(-a));
      outp[oidx] = fused[oidx] + gv * seedt[oidx];
    }
  }
}

// ---------------------------------------------------------------------------
extern "C" void kernel_launch(void* const* d_in, const int* in_sizes, int n_in,
                              void* d_out, int out_size, void* d_ws, size_t ws_size,
                              hipStream_t stream) {
  (void)in_sizes; (void)n_in; (void)out_size; (void)ws_size;
  const float* seed_xyz  = (const float*)d_in[0];
  const float* seed_feat = (const float*)d_in[1];
  const float* vp_rot    = (const float*)d_in[2];
  const float* cW1  = (const float*)d_in[3];
  const float* cb1  = (const float*)d_in[4];
  const float* cg1  = (const float*)d_in[5];
  const float* cbe1 = (const float*)d_in[6];
  const float* cm1  = (const float*)d_in[7];
  const float* cv1  = (const float*)d_in[8];
  const float* cW2  = (const float*)d_in[9];
  const float* cb2  = (const float*)d_in[10];
  const float* cg2  = (const float*)d_in[11];
  const float* cbe2 = (const float*)d_in[12];
  const float* cm2  = (const float*)d_in[13];
  const float* cv2  = (const float*)d_in[14];
  const float* fuse_W  = (const float*)d_in[15];
  const float* fuse_b  = (const float*)d_in[16];
  const float* gate_W  = (const float*)d_in[17];
  const float* gate_b  = (const float*)d_in[18];
  const float* trans_W = (const float*)d_in[19];
  const float* trans_b = (const float*)d_in[20];

  char* ws = (char*)d_ws;
  float4* gxyz4        = (float4*)(ws + 0);          //  2 MB
  float4* xyzb         = (float4*)(ws + 2097152);    // 16 KB
  float* F1            = (float*)(ws + 2113536);     //  8 MB
  float* cat           = (float*)(ws + 10502144);    //  8 MB
  float* seedt         = (float*)(ws + 18890752);    //  2 MB
  float* fusedb        = (float*)(ws + 20987904);    //  2 MB
  int* idx_arr         = (int*)(ws + 23085056);      // 512 KB
  unsigned short* W2b  = (unsigned short*)(ws + 23609344); // 512 KB
  float* bias2c        = (float*)(ws + 24133632);    //  4 KB
  float* s1arr         = (float*)(ws + 24137728);    //  4 KB

  hipLaunchKernelGGL(k0b_prep, dim3(1024), dim3(256), 0, stream,
                     cW1, cb1, cg1, cbe1, cm1, cv1, cW2, cb2, cg2, cbe2, cm2, cv2,
                     W2b, xyzb, bias2c, s1arr);
  hipLaunchKernelGGL(k0_neighbors, dim3(512), dim3(256), 0, stream,
                     seed_xyz, vp_rot, idx_arr, gxyz4);
  hipLaunchKernelGGL(k1_f1, dim3(512), dim3(256), 0, stream,
                     seed_feat, cW1, s1arr, F1);
  hipLaunchKernelGGL(k2_layer2, dim3(2048), dim3(256), 0, stream,
                     idx_arr, gxyz4, F1, W2b, xyzb, bias2c, cat);
  hipLaunchKernelGGL(k3_trans, dim3(128), dim3(256), 0, stream,
                     seed_feat, trans_W, trans_b, seedt);
  hipLaunchKernelGGL(k3_fuse, dim3(128), dim3(256), 0, stream,
                     cat, fuse_W, fuse_b, fusedb);
  hipLaunchKernelGGL(k3_gate, dim3(128), dim3(256), 0, stream,
                     seedt, gate_W, gate_b, fusedb, (float*)d_out);
}

// Round 9
// 407.397 us; speedup vs baseline: 1.1378x; 1.1378x over previous
//
#include <hip/hip_runtime.h>
#include <math.h>

typedef __attribute__((ext_vector_type(8))) short short8;
typedef __attribute__((ext_vector_type(4))) float f32x4;

__device__ __forceinline__ unsigned short bf16_bits(float f) {
  unsigned u = __float_as_uint(f);
  u += 0x7fffu + ((u >> 16) & 1u);
  return (unsigned short)(u >> 16);
}

// ---------------------------------------------------------------- K0b: prep
__global__ __launch_bounds__(256) void k0b_prep(
    const float* __restrict__ W1, const float* __restrict__ b1, const float* __restrict__ g1,
    const float* __restrict__ be1, const float* __restrict__ m1, const float* __restrict__ v1,
    const float* __restrict__ W2, const float* __restrict__ b2, const float* __restrict__ g2,
    const float* __restrict__ be2, const float* __restrict__ m2, const float* __restrict__ v2,
    unsigned short* __restrict__ W2b, float4* __restrict__ xyzb,
    float* __restrict__ bias2c, float* __restrict__ s1arr) {
  const int so = blockIdx.x;      // s*256 + o
  const int j  = threadIdx.x;
  const float s2 = rsqrtf(v2[so] + 1e-5f) * g2[so];
  W2b[(size_t)so * 256 + j] = bf16_bits(W2[(size_t)so * 256 + j] * s2);
  if (j == 0) {
    const float s1 = rsqrtf(v1[so] + 1e-5f) * g1[so];
    const float* wr = W1 + (size_t)so * 515;
    xyzb[so] = make_float4(wr[0] * s1, wr[1] * s1, wr[2] * s1,
                           (b1[so] - m1[so]) * s1 + be1[so]);
    bias2c[so] = (b2[so] - m2[so]) * s2 + be2[so];
    s1arr[so] = s1;
  }
}

// ------------------------------------------------------------ K0: neighbors
__global__ __launch_bounds__(256) void k0_neighbors(
    const float* __restrict__ xyz, const float* __restrict__ rot,
    int* __restrict__ idx_arr, float4* __restrict__ gxyz4) {
  const int wid = threadIdx.x >> 6, lane = threadIdx.x & 63;
  const int gw = blockIdx.x * 4 + wid;
  const int b = gw >> 10, m = gw & 1023;
  const float* pm = xyz + (size_t)(b * 1024 + m) * 3;
  const float cx = pm[0], cy = pm[1], cz = pm[2];
  const float* pr = rot + (size_t)(b * 1024 + m) * 9;
  float R[9];
#pragma unroll
  for (int i = 0; i < 9; ++i) R[i] = pr[i];
  const float radf[4] = {0.0125f, 0.025f, 0.0375f, 0.05f};
  const float rad2[4] = {(float)(0.0125 * 0.0125), (float)(0.025 * 0.025),
                         (float)(0.0375 * 0.0375), (float)(0.05 * 0.05)};
  int cnt[4] = {0, 0, 0, 0};
  int firstn[4] = {0, 0, 0, 0};
  float f0x[4] = {0, 0, 0, 0}, f0y[4] = {0, 0, 0, 0}, f0z[4] = {0, 0, 0, 0};
  for (int n0 = 0; n0 < 1024; n0 += 64) {
    const int n = n0 + lane;
    const float* pn = xyz + (size_t)(b * 1024 + n) * 3;
    const float dx = pn[0] - cx, dy = pn[1] - cy, dz = pn[2] - cz;
    const float l0 = dx * R[0] + dy * R[3] + dz * R[6];
    const float l1 = dx * R[1] + dy * R[4] + dz * R[7];
    const float l2 = dx * R[2] + dy * R[5] + dz * R[8];
    const float d2 = l1 * l1 + l2 * l2;
    const bool hok = (l0 > -0.02f) && (l0 < 0.04f);
#pragma unroll
    for (int s = 0; s < 4; ++s) {
      if (cnt[s] >= 16) continue;                       // wave-uniform
      const bool p = hok && (d2 < rad2[s]);
      const unsigned long long bal = __ballot(p);
      if (bal == 0ull) continue;                        // wave-uniform
      if (cnt[s] == 0) {
        const int src = __builtin_ctzll(bal);
        firstn[s] = n0 + src;
        f0x[s] = __shfl(l0, src);
        f0y[s] = __shfl(l1, src);
        f0z[s] = __shfl(l2, src);
      }
      const int rank = __popcll(bal & ((1ull << lane) - 1ull));
      const int slot = cnt[s] + rank;
      if (p && slot < 16) {
        const size_t base = ((size_t)((s * 2 + b) * 1024 + m)) * 16 + slot;
        idx_arr[base] = n;
        gxyz4[base] = make_float4(l0 / radf[s], l1 / radf[s], l2 / radf[s], 0.f);
      }
      cnt[s] = min(cnt[s] + (int)__popcll(bal), 16);
    }
  }
#pragma unroll
  for (int s = 0; s < 4; ++s) {
    if (lane < 16 && lane >= cnt[s]) {
      const size_t base = ((size_t)((s * 2 + b) * 1024 + m)) * 16 + lane;
      idx_arr[base] = firstn[s];
      gxyz4[base] = make_float4(f0x[s] / radf[s], f0y[s] / radf[s], f0z[s] / radf[s], 0.f);
    }
  }
}

// ---------------------------------------------------------------- K1: F1 GEMM
// F1[s][b][n][o] = sum_c feats[b][c][n] * W1[s][o][3+c] * s1[s][o]
// B-stage coalesced: adjacent lanes read adjacent c (W1 is c-contiguous).
__global__ __launch_bounds__(256) void k1_f1(
    const float* __restrict__ feats, const float* __restrict__ W1,
    const float* __restrict__ s1arr, float* __restrict__ F1) {
  __shared__ float At[16][68];
  __shared__ float Bt[16][68];
  const int bid = blockIdx.x;
  const int ogt = bid & 15, nt = (bid >> 4) & 15, b = bid >> 8;
  const int og0 = ogt * 64, n0 = nt * 64;
  const int tx = threadIdx.x & 15, ty = threadIdx.x >> 4;
  float acc[4][4] = {};
  for (int c0 = 0; c0 < 512; c0 += 16) {
#pragma unroll
    for (int it = 0; it < 4; ++it) {
      const int t = threadIdx.x + it * 256;
      { const int cc = t >> 6, nn = t & 63;
        At[cc][nn] = feats[((size_t)(b * 512 + c0 + cc)) * 1024 + n0 + nn]; }
      { const int cc = t & 15, nn = t >> 4;            // coalesced along c
        const int og = og0 + nn;
        Bt[cc][nn] = W1[(size_t)og * 515 + 3 + c0 + cc] * s1arr[og]; }
    }
    __syncthreads();
#pragma unroll
    for (int cc = 0; cc < 16; ++cc) {
      const float4 a = *(const float4*)&At[cc][ty * 4];
      const float4 bv = *(const float4*)&Bt[cc][tx * 4];
      const float av[4] = {a.x, a.y, a.z, a.w};
      const float bw[4] = {bv.x, bv.y, bv.z, bv.w};
#pragma unroll
      for (int i = 0; i < 4; ++i)
#pragma unroll
        for (int j = 0; j < 4; ++j) acc[i][j] = fmaf(av[i], bw[j], acc[i][j]);
    }
    __syncthreads();
  }
  const int s = og0 >> 8;
  const int obase = (og0 & 255) + tx * 4;
#pragma unroll
  for (int i = 0; i < 4; ++i) {
    const int n = n0 + ty * 4 + i;
    float4 w;
    w.x = acc[i][0]; w.y = acc[i][1]; w.z = acc[i][2]; w.w = acc[i][3];
    *(float4*)&F1[(((size_t)(s * 2 + b)) * 1024 + n) * 256 + obase] = w;
  }
}

// ------------------------------------------------- K2: finalize L1 + L2 MFMA + max
// v2: deep register prefetch. All 16 F1 gathers issued up-front; per-ks the
// 16 B-fragments load into bf[16] before the MFMA chain (overlap VALU build).
__global__ __launch_bounds__(256) void k2_layer2(
    const int* __restrict__ idx_arr, const float4* __restrict__ gxyz4,
    const float* __restrict__ F1, const unsigned short* __restrict__ W2b,
    const float4* __restrict__ xyzb, const float* __restrict__ bias2c,
    float* __restrict__ cat) {
  const int wid = threadIdx.x >> 6, lane = threadIdx.x & 63;
  const int bid = blockIdx.x;
  const int mg = bid & 255, b = (bid >> 8) & 1, s = bid >> 9;
  const int m = mg * 4 + wid;
  const int r = lane & 15, hi = lane >> 4;
  const size_t sb = (size_t)((s * 2 + b) * 1024 + m) * 16 + r;
  const int n = idx_arr[sb];
  const float4 g = gxyz4[sb];
  const float* __restrict__ f1row = F1 + ((size_t)((s * 2 + b) * 1024) + n) * 256;
  const unsigned short* __restrict__ w2s = W2b + (size_t)s * 65536;
  const float4* __restrict__ xbs = xyzb + s * 256;

  // -------- prefetch: all F1 gather data for this lane (16 float4, in flight)
  float4 pf[16];
#pragma unroll
  for (int ks = 0; ks < 8; ++ks) {
    const int j0 = ks * 32 + hi * 8;
    pf[ks * 2]     = *(const float4*)(f1row + j0);
    pf[ks * 2 + 1] = *(const float4*)(f1row + j0 + 4);
  }

  f32x4 acc[16];
#pragma unroll
  for (int t = 0; t < 16; ++t) { acc[t][0] = 0.f; acc[t][1] = 0.f; acc[t][2] = 0.f; acc[t][3] = 0.f; }

#pragma unroll
  for (int ks = 0; ks < 8; ++ks) {
    const int j0 = ks * 32 + hi * 8;
    // B fragments first: 16 independent 16B loads, overlap the VALU build below
    short8 bf[16];
#pragma unroll
    for (int t = 0; t < 16; ++t)
      bf[t] = *(const short8*)(w2s + ((size_t)(t * 16 + r)) * 256 + j0);
    // xyz-part coefficients (tiny, L1-hot)
    float4 xb[8];
#pragma unroll
    for (int i = 0; i < 8; ++i) xb[i] = xbs[j0 + i];
    // A fragment: finalize layer-1 (xyz dot + bias + ReLU) and pack bf16
    const float4 fa = pf[ks * 2], fb = pf[ks * 2 + 1];
    const float fv[8] = {fa.x, fa.y, fa.z, fa.w, fb.x, fb.y, fb.z, fb.w};
    short8 af;
#pragma unroll
    for (int i = 0; i < 8; ++i) {
      float v = fv[i] + xb[i].w;
      v = fmaf(g.x, xb[i].x, v);
      v = fmaf(g.y, xb[i].y, v);
      v = fmaf(g.z, xb[i].z, v);
      v = fmaxf(v, 0.f);
      af[i] = (short)bf16_bits(v);
    }
#pragma unroll
    for (int t = 0; t < 16; ++t)
      acc[t] = __builtin_amdgcn_mfma_f32_16x16x32_bf16(af, bf[t], acc[t], 0, 0, 0);
  }

  float* __restrict__ catrow = cat + ((size_t)(b * 1024 + m)) * 1024 + s * 256;
#pragma unroll
  for (int t = 0; t < 16; ++t) {
    const float bc = bias2c[s * 256 + t * 16 + r];
    float mv = fmaxf(acc[t][0] + bc, 0.f);
    mv = fmaxf(mv, fmaxf(acc[t][1] + bc, 0.f));
    mv = fmaxf(mv, fmaxf(acc[t][2] + bc, 0.f));
    mv = fmaxf(mv, fmaxf(acc[t][3] + bc, 0.f));
    mv = fmaxf(mv, __shfl_xor(mv, 16));
    mv = fmaxf(mv, __shfl_xor(mv, 32));
    if (hi == 0) catrow[t * 16 + r] = mv;
  }
}

// ------------------------------------------------------------ K3a: trans GEMM
__global__ __launch_bounds__(256) void k3_trans(
    const float* __restrict__ feats, const float* __restrict__ W,
    const float* __restrict__ bias, float* __restrict__ outp) {
  __shared__ float At[16][68];
  __shared__ float Bt[16][68];
  const int bid = blockIdx.x;
  const int ot = bid & 3, nt = (bid >> 2) & 15, b = bid >> 6;
  const int og0 = ot * 64, m0 = nt * 64;
  const int tx = threadIdx.x & 15, ty = threadIdx.x >> 4;
  float acc[4][4] = {};
  for (int c0 = 0; c0 < 512; c0 += 16) {
#pragma unroll
    for (int it = 0; it < 4; ++it) {
      const int t = threadIdx.x + it * 256;
      { const int cc = t >> 6, nn = t & 63;
        At[cc][nn] = feats[((size_t)(b * 512 + c0 + cc)) * 1024 + m0 + nn]; }
      { const int cc = t & 15, nn = t >> 4;            // coalesced along c
        Bt[cc][nn] = W[(size_t)(og0 + nn) * 512 + c0 + cc]; }
    }
    __syncthreads();
#pragma unroll
    for (int cc = 0; cc < 16; ++cc) {
      const float4 a = *(const float4*)&At[cc][ty * 4];
      const float4 bv = *(const float4*)&Bt[cc][tx * 4];
      const float av[4] = {a.x, a.y, a.z, a.w};
      const float bw[4] = {bv.x, bv.y, bv.z, bv.w};
#pragma unroll
      for (int i = 0; i < 4; ++i)
#pragma unroll
        for (int j = 0; j < 4; ++j) acc[i][j] = fmaf(av[i], bw[j], acc[i][j]);
    }
    __syncthreads();
  }
#pragma unroll
  for (int j = 0; j < 4; ++j) {
    const int og = og0 + tx * 4 + j;
    const float bb = bias[og];
#pragma unroll
    for (int i = 0; i < 4; ++i)
      outp[((size_t)(b * 256 + og)) * 1024 + m0 + ty * 4 + i] = acc[i][j] + bb;
  }
}

// ------------------------------------------------------------- K3b: fuse GEMM
__global__ __launch_bounds__(256) void k3_fuse(
    const float* __restrict__ cat, const float* __restrict__ W,
    const float* __restrict__ bias, float* __restrict__ outp) {
  __shared__ float At[16][68];
  __shared__ float Bt[16][68];
  const int bid = blockIdx.x;
  const int ot = bid & 3, nt = (bid >> 2) & 15, b = bid >> 6;
  const int og0 = ot * 64, m0 = nt * 64;
  const int tx = threadIdx.x & 15, ty = threadIdx.x >> 4;
  float acc[4][4] = {};
  for (int c0 = 0; c0 < 1024; c0 += 16) {
#pragma unroll
    for (int it = 0; it < 4; ++it) {
      const int t = threadIdx.x + it * 256;
      { const int mm = t >> 4, cj = t & 15;            // transpose-stage A (coalesced)
        At[cj][mm] = cat[((size_t)(b * 1024 + m0 + mm)) * 1024 + c0 + cj]; }
      { const int cc = t & 15, nn = t >> 4;            // coalesced along c
        Bt[cc][nn] = W[(size_t)(og0 + nn) * 1024 + c0 + cc]; }
    }
    __syncthreads();
#pragma unroll
    for (int cc = 0; cc < 16; ++cc) {
      const float4 a = *(const float4*)&At[cc][ty * 4];
      const float4 bv = *(const float4*)&Bt[cc][tx * 4];
      const float av[4] = {a.x, a.y, a.z, a.w};
      const float bw[4] = {bv.x, bv.y, bv.z, bv.w};
#pragma unroll
      for (int i = 0; i < 4; ++i)
#pragma unroll
        for (int j = 0; j < 4; ++j) acc[i][j] = fmaf(av[i], bw[j], acc[i][j]);
    }
    __syncthreads();
  }
#pragma unroll
  for (int j = 0; j < 4; ++j) {
    const int og = og0 + tx * 4 + j;
    const float bb = bias[og];
#pragma unroll
    for (int i = 0; i < 4; ++i)
      outp[((size_t)(b * 256 + og)) * 1024 + m0 + ty * 4 + i] = acc[i][j] + bb;
  }
}

// --------------------------------------------- K3c: gate GEMM + final combine
__global__ __launch_bounds__(256) void k3_gate(
    const float* __restrict__ seedt, const float* __restrict__ W,
    const float* __restrict__ bias, const float* __restrict__ fused,
    float* __restrict__ outp) {
  __shared__ float At[16][68];
  __shared__ float Bt[16][68];
  const int bid = blockIdx.x;
  const int ot = bid & 3, nt = (bid >> 2) & 15, b = bid >> 6;
  const int og0 = ot * 64, m0 = nt * 64;
  const int tx = threadIdx.x & 15, ty = threadIdx.x >> 4;
  float acc[4][4] = {};
  for (int c0 = 0; c0 < 256; c0 += 16) {
#pragma unroll
    for (int it = 0; it < 4; ++it) {
      const int t = threadIdx.x + it * 256;
      { const int cc = t >> 6, nn = t & 63;
        At[cc][nn] = seedt[((size_t)(b * 256 + c0 + cc)) * 1024 + m0 + nn]; }
      { const int cc = t & 15, nn = t >> 4;            // coalesced along c
        Bt[cc][nn] = W[(size_t)(og0 + nn) * 256 + c0 + cc]; }
    }
    __syncthreads();
#pragma unroll
    for (int cc = 0; cc < 16; ++cc) {
      const float4 a = *(const float4*)&At[cc][ty * 4];
      const float4 bv = *(const float4*)&Bt[cc][tx * 4];
      const float av[4] = {a.x, a.y, a.z, a.w};
      const float bw[4] = {bv.x, bv.y, bv.z, bv.w};
#pragma unroll
      for (int i = 0; i < 4; ++i)
#pragma unroll
        for (int j = 0; j < 4; ++j) acc[i][j] = fmaf(av[i], bw[j], acc[i][j]);
    }
    __syncthreads();
  }
#pragma unroll
  for (int j = 0; j < 4; ++j) {
    const int og = og0 + tx * 4 + j;
    const float gb = bias[og];
#pragma unroll
    for (int i = 0; i < 4; ++i) {
      const size_t oidx = ((size_t)(b * 256 + og)) * 1024 + m0 + ty * 4 + i;
      const float a = acc[i][j] + gb;
      const float gv = 1.f / (1.f + expf(-a));
      outp[oidx] = fused[oidx] + gv * seedt[oidx];
    }
  }
}

// ---------------------------------------------------------------------------
extern "C" void kernel_launch(void* const* d_in, const int* in_sizes, int n_in,
                              void* d_out, int out_size, void* d_ws, size_t ws_size,
                              hipStream_t stream) {
  (void)in_sizes; (void)n_in; (void)out_size; (void)ws_size;
  const float* seed_xyz  = (const float*)d_in[0];
  const float* seed_feat = (const float*)d_in[1];
  const float* vp_rot    = (const float*)d_in[2];
  const float* cW1  = (const float*)d_in[3];
  const float* cb1  = (const float*)d_in[4];
  const float* cg1  = (const float*)d_in[5];
  const float* cbe1 = (const float*)d_in[6];
  const float* cm1  = (const float*)d_in[7];
  const float* cv1  = (const float*)d_in[8];
  const float* cW2  = (const float*)d_in[9];
  const float* cb2  = (const float*)d_in[10];
  const float* cg2  = (const float*)d_in[11];
  const float* cbe2 = (const float*)d_in[12];
  const float* cm2  = (const float*)d_in[13];
  const float* cv2  = (const float*)d_in[14];
  const float* fuse_W  = (const float*)d_in[15];
  const float* fuse_b  = (const float*)d_in[16];
  const float* gate_W  = (const float*)d_in[17];
  const float* gate_b  = (const float*)d_in[18];
  const float* trans_W = (const float*)d_in[19];
  const float* trans_b = (const float*)d_in[20];

  char* ws = (char*)d_ws;
  float4* gxyz4        = (float4*)(ws + 0);          //  2 MB
  float4* xyzb         = (float4*)(ws + 2097152);    // 16 KB
  float* F1            = (float*)(ws + 2113536);     //  8 MB
  float* cat           = (float*)(ws + 10502144);    //  8 MB
  float* seedt         = (float*)(ws + 18890752);    //  2 MB
  float* fusedb        = (float*)(ws + 20987904);    //  2 MB
  int* idx_arr         = (int*)(ws + 23085056);      // 512 KB
  unsigned short* W2b  = (unsigned short*)(ws + 23609344); // 512 KB
  float* bias2c        = (float*)(ws + 24133632);    //  4 KB
  float* s1arr         = (float*)(ws + 24137728);    //  4 KB

  hipLaunchKernelGGL(k0b_prep, dim3(1024), dim3(256), 0, stream,
                     cW1, cb1, cg1, cbe1, cm1, cv1, cW2, cb2, cg2, cbe2, cm2, cv2,
                     W2b, xyzb, bias2c, s1arr);
  hipLaunchKernelGGL(k0_neighbors, dim3(512), dim3(256), 0, stream,
                     seed_xyz, vp_rot, idx_arr, gxyz4);
  hipLaunchKernelGGL(k1_f1, dim3(512), dim3(256), 0, stream,
                     seed_feat, cW1, s1arr, F1);
  hipLaunchKernelGGL(k2_layer2, dim3(2048), dim3(256), 0, stream,
                     idx_arr, gxyz4, F1, W2b, xyzb, bias2c, cat);
  hipLaunchKernelGGL(k3_trans, dim3(128), dim3(256), 0, stream,
                     seed_feat, trans_W, trans_b, seedt);
  hipLaunchKernelGGL(k3_fuse, dim3(128), dim3(256), 0, stream,
                     cat, fuse_W, fuse_b, fusedb);
  hipLaunchKernelGGL(k3_gate, dim3(128), dim3(256), 0, stream,
                     seedt, gate_W, gate_b, fusedb, (float*)d_out);
}

// Round 12
// 311.086 us; speedup vs baseline: 1.4900x; 1.3096x over previous
//
#include <hip/hip_runtime.h>
#include <math.h>

typedef __attribute__((ext_vector_type(8))) short short8;
typedef __attribute__((ext_vector_type(4))) float f32x4;

__device__ __forceinline__ unsigned short bf16_bits(float f) {
  unsigned u = __float_as_uint(f);
  u += 0x7fffu + ((u >> 16) & 1u);
  return (unsigned short)(u >> 16);
}

// async global->LDS, 16B per lane: LDS dest = uniform base + lane*16
__device__ __forceinline__ void gload_lds16(const unsigned short* gp, unsigned short* lp) {
  __builtin_amdgcn_global_load_lds(
      (const __attribute__((address_space(1))) unsigned int*)gp,
      (__attribute__((address_space(3))) unsigned int*)lp, 16, 0, 0);
}

// ---------------------------------------------------------------- K0b: prep
// Fold BN scales; W2 -> bf16 in MFMA-FRAGMENT ORDER:
// W2f[s][ks][t][l] (16B) = W2'[o=t*16+(l&15)][k=ks*32+(l>>4)*8 .. +8)
__global__ __launch_bounds__(256) void k0b_prep(
    const float* __restrict__ W1, const float* __restrict__ b1, const float* __restrict__ g1,
    const float* __restrict__ be1, const float* __restrict__ m1, const float* __restrict__ v1,
    const float* __restrict__ W2, const float* __restrict__ b2, const float* __restrict__ g2,
    const float* __restrict__ be2, const float* __restrict__ m2, const float* __restrict__ v2,
    unsigned short* __restrict__ W2f, float4* __restrict__ xyzb,
    float* __restrict__ bias2c, float* __restrict__ s1arr) {
  const int so = blockIdx.x;      // s*256 + o
  const int j  = threadIdx.x;     // k
  const int s = so >> 8, o = so & 255;
  const float s2 = rsqrtf(v2[so] + 1e-5f) * g2[so];
  const int t = o >> 4, r = o & 15;
  const int ks = j >> 5, hi = (j >> 3) & 3, i = j & 7;
  const int l = hi * 16 + r;
  W2f[(size_t)s * 65536 + (size_t)((ks * 16 + t) << 9) + l * 8 + i] =
      bf16_bits(W2[(size_t)so * 256 + j] * s2);
  if (j == 0) {
    const float s1 = rsqrtf(v1[so] + 1e-5f) * g1[so];
    const float* wr = W1 + (size_t)so * 515;
    xyzb[so] = make_float4(wr[0] * s1, wr[1] * s1, wr[2] * s1,
                           (b1[so] - m1[so]) * s1 + be1[so]);
    bias2c[so] = (b2[so] - m2[so]) * s2 + be2[so];
    s1arr[so] = s1;
  }
}

// ------------------------------------------------------------ K0: neighbors
__global__ __launch_bounds__(256) void k0_neighbors(
    const float* __restrict__ xyz, const float* __restrict__ rot,
    int* __restrict__ idx_arr, float4* __restrict__ gxyz4) {
  const int wid = threadIdx.x >> 6, lane = threadIdx.x & 63;
  const int gw = blockIdx.x * 4 + wid;
  const int b = gw >> 10, m = gw & 1023;
  const float* pm = xyz + (size_t)(b * 1024 + m) * 3;
  const float cx = pm[0], cy = pm[1], cz = pm[2];
  const float* pr = rot + (size_t)(b * 1024 + m) * 9;
  float R[9];
#pragma unroll
  for (int i = 0; i < 9; ++i) R[i] = pr[i];
  const float radf[4] = {0.0125f, 0.025f, 0.0375f, 0.05f};
  const float rad2[4] = {(float)(0.0125 * 0.0125), (float)(0.025 * 0.025),
                         (float)(0.0375 * 0.0375), (float)(0.05 * 0.05)};
  int cnt[4] = {0, 0, 0, 0};
  int firstn[4] = {0, 0, 0, 0};
  float f0x[4] = {0, 0, 0, 0}, f0y[4] = {0, 0, 0, 0}, f0z[4] = {0, 0, 0, 0};
  for (int n0 = 0; n0 < 1024; n0 += 64) {
    const int n = n0 + lane;
    const float* pn = xyz + (size_t)(b * 1024 + n) * 3;
    const float dx = pn[0] - cx, dy = pn[1] - cy, dz = pn[2] - cz;
    const float l0 = dx * R[0] + dy * R[3] + dz * R[6];
    const float l1 = dx * R[1] + dy * R[4] + dz * R[7];
    const float l2 = dx * R[2] + dy * R[5] + dz * R[8];
    const float d2 = l1 * l1 + l2 * l2;
    const bool hok = (l0 > -0.02f) && (l0 < 0.04f);
#pragma unroll
    for (int s = 0; s < 4; ++s) {
      if (cnt[s] >= 16) continue;                       // wave-uniform
      const bool p = hok && (d2 < rad2[s]);
      const unsigned long long bal = __ballot(p);
      if (bal == 0ull) continue;                        // wave-uniform
      if (cnt[s] == 0) {
        const int src = __builtin_ctzll(bal);
        firstn[s] = n0 + src;
        f0x[s] = __shfl(l0, src);
        f0y[s] = __shfl(l1, src);
        f0z[s] = __shfl(l2, src);
      }
      const int rank = __popcll(bal & ((1ull << lane) - 1ull));
      const int slot = cnt[s] + rank;
      if (p && slot < 16) {
        const size_t base = ((size_t)((s * 2 + b) * 1024 + m)) * 16 + slot;
        idx_arr[base] = n;
        gxyz4[base] = make_float4(l0 / radf[s], l1 / radf[s], l2 / radf[s], 0.f);
      }
      cnt[s] = min(cnt[s] + (int)__popcll(bal), 16);
    }
  }
#pragma unroll
  for (int s = 0; s < 4; ++s) {
    if (lane < 16 && lane >= cnt[s]) {
      const size_t base = ((size_t)((s * 2 + b) * 1024 + m)) * 16 + lane;
      idx_arr[base] = firstn[s];
      gxyz4[base] = make_float4(f0x[s] / radf[s], f0y[s] / radf[s], f0z[s] / radf[s], 0.f);
    }
  }
}

// ---------------------------------------------------------------- K1: F1 GEMM
__global__ __launch_bounds__(256) void k1_f1(
    const float* __restrict__ feats, const float* __restrict__ W1,
    const float* __restrict__ s1arr, float* __restrict__ F1) {
  __shared__ float At[16][68];
  __shared__ float Bt[16][68];
  const int bid = blockIdx.x;
  const int ogt = bid & 15, nt = (bid >> 4) & 15, b = bid >> 8;
  const int og0 = ogt * 64, n0 = nt * 64;
  const int tx = threadIdx.x & 15, ty = threadIdx.x >> 4;
  float acc[4][4] = {};
  for (int c0 = 0; c0 < 512; c0 += 16) {
#pragma unroll
    for (int it = 0; it < 4; ++it) {
      const int t = threadIdx.x + it * 256;
      { const int cc = t >> 6, nn = t & 63;
        At[cc][nn] = feats[((size_t)(b * 512 + c0 + cc)) * 1024 + n0 + nn]; }
      { const int cc = t & 15, nn = t >> 4;            // coalesced along c
        const int og = og0 + nn;
        Bt[cc][nn] = W1[(size_t)og * 515 + 3 + c0 + cc] * s1arr[og]; }
    }
    __syncthreads();
#pragma unroll
    for (int cc = 0; cc < 16; ++cc) {
      const float4 a = *(const float4*)&At[cc][ty * 4];
      const float4 bv = *(const float4*)&Bt[cc][tx * 4];
      const float av[4] = {a.x, a.y, a.z, a.w};
      const float bw[4] = {bv.x, bv.y, bv.z, bv.w};
#pragma unroll
      for (int i = 0; i < 4; ++i)
#pragma unroll
        for (int j = 0; j < 4; ++j) acc[i][j] = fmaf(av[i], bw[j], acc[i][j]);
    }
    __syncthreads();
  }
  const int s = og0 >> 8;
  const int obase = (og0 & 255) + tx * 4;
#pragma unroll
  for (int i = 0; i < 4; ++i) {
    const int n = n0 + ty * 4 + i;
    float4 w;
    w.x = acc[i][0]; w.y = acc[i][1]; w.z = acc[i][2]; w.w = acc[i][3];
    *(float4*)&F1[(((size_t)(s * 2 + b)) * 1024 + n) * 256 + obase] = w;
  }
}

// ------------------------------------------------- K2: finalize L1 + L2 MFMA + max
// v3: W2 staged via async global_load_lds (fragment order, double-buffered LDS).
// Per ks: issue 4x1KB async stages for ks+1, compute ks from LDS (conflict-free
// ds_read_b128: consecutive lanes -> consecutive 16B), barrier drains.
__global__ __launch_bounds__(256) void k2_layer2(
    const int* __restrict__ idx_arr, const float4* __restrict__ gxyz4,
    const float* __restrict__ F1, const unsigned short* __restrict__ W2f,
    const float4* __restrict__ xyzb, const float* __restrict__ bias2c,
    float* __restrict__ cat) {
  __shared__ unsigned short sbuf[2][8192];   // 2 x 16 KB
  const int wid = threadIdx.x >> 6, lane = threadIdx.x & 63;
  const int bid = blockIdx.x;
  const int mg = bid & 255, b = (bid >> 8) & 1, s = bid >> 9;
  const int m = mg * 4 + wid;
  const int r = lane & 15, hi = lane >> 4;
  const size_t sb = (size_t)((s * 2 + b) * 1024 + m) * 16 + r;
  const int n = idx_arr[sb];
  const float4 g = gxyz4[sb];
  const float* __restrict__ f1row = F1 + ((size_t)((s * 2 + b) * 1024) + n) * 256;
  const unsigned short* __restrict__ w2f = W2f + (size_t)s * 65536;
  const float4* __restrict__ xbs = xyzb + s * 256;

  // F1 gathers in flight alongside prologue stage
  float4 pf[16];
#pragma unroll
  for (int ks = 0; ks < 8; ++ks) {
    const int j0 = ks * 32 + hi * 8;
    pf[ks * 2]     = *(const float4*)(f1row + j0);
    pf[ks * 2 + 1] = *(const float4*)(f1row + j0 + 4);
  }

  // prologue: stage ks=0 into sbuf[0]
#pragma unroll
  for (int tt = 0; tt < 4; ++tt) {
    const int t = wid * 4 + tt;
    gload_lds16(w2f + ((size_t)t << 9) + lane * 8, &sbuf[0][t * 512]);
  }
  __syncthreads();

  f32x4 acc[16];
#pragma unroll
  for (int t = 0; t < 16; ++t) { acc[t][0] = 0.f; acc[t][1] = 0.f; acc[t][2] = 0.f; acc[t][3] = 0.f; }

#pragma unroll
  for (int ks = 0; ks < 8; ++ks) {
    const int cur = ks & 1;
    if (ks < 7) {
#pragma unroll
      for (int tt = 0; tt < 4; ++tt) {
        const int t = wid * 4 + tt;
        gload_lds16(w2f + ((size_t)((ks + 1) * 16 + t) << 9) + lane * 8,
                    &sbuf[cur ^ 1][t * 512]);
      }
    }
    const int j0 = ks * 32 + hi * 8;
    const float4 fa = pf[ks * 2], fb = pf[ks * 2 + 1];
    const float fv[8] = {fa.x, fa.y, fa.z, fa.w, fb.x, fb.y, fb.z, fb.w};
    short8 af;
#pragma unroll
    for (int i = 0; i < 8; ++i) {
      const float4 xb = xbs[j0 + i];
      float v = fv[i] + xb.w;
      v = fmaf(g.x, xb.x, v);
      v = fmaf(g.y, xb.y, v);
      v = fmaf(g.z, xb.z, v);
      v = fmaxf(v, 0.f);
      af[i] = (short)bf16_bits(v);
    }
#pragma unroll
    for (int t = 0; t < 16; ++t) {
      const short8 bfv = *(const short8*)&sbuf[cur][t * 512 + lane * 8];
      acc[t] = __builtin_amdgcn_mfma_f32_16x16x32_bf16(af, bfv, acc[t], 0, 0, 0);
    }
    __syncthreads();
  }

  float* __restrict__ catrow = cat + ((size_t)(b * 1024 + m)) * 1024 + s * 256;
#pragma unroll
  for (int t = 0; t < 16; ++t) {
    const float bc = bias2c[s * 256 + t * 16 + r];
    float mv = fmaxf(acc[t][0] + bc, 0.f);
    mv = fmaxf(mv, fmaxf(acc[t][1] + bc, 0.f));
    mv = fmaxf(mv, fmaxf(acc[t][2] + bc, 0.f));
    mv = fmaxf(mv, fmaxf(acc[t][3] + bc, 0.f));
    mv = fmaxf(mv, __shfl_xor(mv, 16));
    mv = fmaxf(mv, __shfl_xor(mv, 32));
    if (hi == 0) catrow[t * 16 + r] = mv;
  }
}

// ------------------------------------------------------------ K3a: trans GEMM
__global__ __launch_bounds__(256) void k3_trans(
    const float* __restrict__ feats, const float* __restrict__ W,
    const float* __restrict__ bias, float* __restrict__ outp) {
  __shared__ float At[16][68];
  __shared__ float Bt[16][68];
  const int bid = blockIdx.x;
  const int ot = bid & 3, nt = (bid >> 2) & 15, b = bid >> 6;
  const int og0 = ot * 64, m0 = nt * 64;
  const int tx = threadIdx.x & 15, ty = threadIdx.x >> 4;
  float acc[4][4] = {};
  for (int c0 = 0; c0 < 512; c0 += 16) {
#pragma unroll
    for (int it = 0; it < 4; ++it) {
      const int t = threadIdx.x + it * 256;
      { const int cc = t >> 6, nn = t & 63;
        At[cc][nn] = feats[((size_t)(b * 512 + c0 + cc)) * 1024 + m0 + nn]; }
      { const int cc = t & 15, nn = t >> 4;            // coalesced along c
        Bt[cc][nn] = W[(size_t)(og0 + nn) * 512 + c0 + cc]; }
    }
    __syncthreads();
#pragma unroll
    for (int cc = 0; cc < 16; ++cc) {
      const float4 a = *(const float4*)&At[cc][ty * 4];
      const float4 bv = *(const float4*)&Bt[cc][tx * 4];
      const float av[4] = {a.x, a.y, a.z, a.w};
      const float bw[4] = {bv.x, bv.y, bv.z, bv.w};
#pragma unroll
      for (int i = 0; i < 4; ++i)
#pragma unroll
        for (int j = 0; j < 4; ++j) acc[i][j] = fmaf(av[i], bw[j], acc[i][j]);
    }
    __syncthreads();
  }
#pragma unroll
  for (int j = 0; j < 4; ++j) {
    const int og = og0 + tx * 4 + j;
    const float bb = bias[og];
#pragma unroll
    for (int i = 0; i < 4; ++i)
      outp[((size_t)(b * 256 + og)) * 1024 + m0 + ty * 4 + i] = acc[i][j] + bb;
  }
}

// ------------------------------------------------------------- K3b: fuse GEMM
__global__ __launch_bounds__(256) void k3_fuse(
    const float* __restrict__ cat, const float* __restrict__ W,
    const float* __restrict__ bias, float* __restrict__ outp) {
  __shared__ float At[16][68];
  __shared__ float Bt[16][68];
  const int bid = blockIdx.x;
  const int ot = bid & 3, nt = (bid >> 2) & 15, b = bid >> 6;
  const int og0 = ot * 64, m0 = nt * 64;
  const int tx = threadIdx.x & 15, ty = threadIdx.x >> 4;
  float acc[4][4] = {};
  for (int c0 = 0; c0 < 1024; c0 += 16) {
#pragma unroll
    for (int it = 0; it < 4; ++it) {
      const int t = threadIdx.x + it * 256;
      { const int mm = t >> 4, cj = t & 15;            // transpose-stage A (coalesced)
        At[cj][mm] = cat[((size_t)(b * 1024 + m0 + mm)) * 1024 + c0 + cj]; }
      { const int cc = t & 15, nn = t >> 4;            // coalesced along c
        Bt[cc][nn] = W[(size_t)(og0 + nn) * 1024 + c0 + cc]; }
    }
    __syncthreads();
#pragma unroll
    for (int cc = 0; cc < 16; ++cc) {
      const float4 a = *(const float4*)&At[cc][ty * 4];
      const float4 bv = *(const float4*)&Bt[cc][tx * 4];
      const float av[4] = {a.x, a.y, a.z, a.w};
      const float bw[4] = {bv.x, bv.y, bv.z, bv.w};
#pragma unroll
      for (int i = 0; i < 4; ++i)
#pragma unroll
        for (int j = 0; j < 4; ++j) acc[i][j] = fmaf(av[i], bw[j], acc[i][j]);
    }
    __syncthreads();
  }
#pragma unroll
  for (int j = 0; j < 4; ++j) {
    const int og = og0 + tx * 4 + j;
    const float bb = bias[og];
#pragma unroll
    for (int i = 0; i < 4; ++i)
      outp[((size_t)(b * 256 + og)) * 1024 + m0 + ty * 4 + i] = acc[i][j] + bb;
  }
}

// --------------------------------------------- K3c: gate GEMM + final combine
__global__ __launch_bounds__(256) void k3_gate(
    const float* __restrict__ seedt, const float* __restrict__ W,
    const float* __restrict__ bias, const float* __restrict__ fused,
    float* __restrict__ outp) {
  __shared__ float At[16][68];
  __shared__ float Bt[16][68];
  const int bid = blockIdx.x;
  const int ot = bid & 3, nt = (bid >> 2) & 15, b = bid >> 6;
  const int og0 = ot * 64, m0 = nt * 64;
  const int tx = threadIdx.x & 15, ty = threadIdx.x >> 4;
  float acc[4][4] = {};
  for (int c0 = 0; c0 < 256; c0 += 16) {
#pragma unroll
    for (int it = 0; it < 4; ++it) {
      const int t = threadIdx.x + it * 256;
      { const int cc = t >> 6, nn = t & 63;
        At[cc][nn] = seedt[((size_t)(b * 256 + c0 + cc)) * 1024 + m0 + nn]; }
      { const int cc = t & 15, nn = t >> 4;            // coalesced along c
        Bt[cc][nn] = W[(size_t)(og0 + nn) * 256 + c0 + cc]; }
    }
    __syncthreads();
#pragma unroll
    for (int cc = 0; cc < 16; ++cc) {
      const float4 a = *(const float4*)&At[cc][ty * 4];
      const float4 bv = *(const float4*)&Bt[cc][tx * 4];
      const float av[4] = {a.x, a.y, a.z, a.w};
      const float bw[4] = {bv.x, bv.y, bv.z, bv.w};
#pragma unroll
      for (int i = 0; i < 4; ++i)
#pragma unroll
        for (int j = 0; j < 4; ++j) acc[i][j] = fmaf(av[i], bw[j], acc[i][j]);
    }
    __syncthreads();
  }
#pragma unroll
  for (int j = 0; j < 4; ++j) {
    const int og = og0 + tx * 4 + j;
    const float gb = bias[og];
#pragma unroll
    for (int i = 0; i < 4; ++i) {
      const size_t oidx = ((size_t)(b * 256 + og)) * 1024 + m0 + ty * 4 + i;
      const float a = acc[i][j] + gb;
      const float gv = 1.f / (1.f + expf(-a));
      outp[oidx] = fused[oidx] + gv * seedt[oidx];
    }
  }
}

// ---------------------------------------------------------------------------
extern "C" void kernel_launch(void* const* d_in, const int* in_sizes, int n_in,
                              void* d_out, int out_size, void* d_ws, size_t ws_size,
                              hipStream_t stream) {
  (void)in_sizes; (void)n_in; (void)out_size; (void)ws_size;
  const float* seed_xyz  = (const float*)d_in[0];
  const float* seed_feat = (const float*)d_in[1];
  const float* vp_rot    = (const float*)d_in[2];
  const float* cW1  = (const float*)d_in[3];
  const float* cb1  = (const float*)d_in[4];
  const float* cg1  = (const float*)d_in[5];
  const float* cbe1 = (const float*)d_in[6];
  const float* cm1  = (const float*)d_in[7];
  const float* cv1  = (const float*)d_in[8];
  const float* cW2  = (const float*)d_in[9];
  const float* cb2  = (const float*)d_in[10];
  const float* cg2  = (const float*)d_in[11];
  const float* cbe2 = (const float*)d_in[12];
  const float* cm2  = (const float*)d_in[13];
  const float* cv2  = (const float*)d_in[14];
  const float* fuse_W  = (const float*)d_in[15];
  const float* fuse_b  = (const float*)d_in[16];
  const float* gate_W  = (const float*)d_in[17];
  const float* gate_b  = (const float*)d_in[18];
  const float* trans_W = (const float*)d_in[19];
  const float* trans_b = (const float*)d_in[20];

  char* ws = (char*)d_ws;
  float4* gxyz4        = (float4*)(ws + 0);          //  2 MB
  float4* xyzb         = (float4*)(ws + 2097152);    // 16 KB
  float* F1            = (float*)(ws + 2113536);     //  8 MB
  float* cat           = (float*)(ws + 10502144);    //  8 MB
  float* seedt         = (float*)(ws + 18890752);    //  2 MB
  float* fusedb        = (float*)(ws + 20987904);    //  2 MB
  int* idx_arr         = (int*)(ws + 23085056);      // 512 KB
  unsigned short* W2f  = (unsigned short*)(ws + 23609344); // 512 KB (fragment order)
  float* bias2c        = (float*)(ws + 24133632);    //  4 KB
  float* s1arr         = (float*)(ws + 24137728);    //  4 KB

  hipLaunchKernelGGL(k0b_prep, dim3(1024), dim3(256), 0, stream,
                     cW1, cb1, cg1, cbe1, cm1, cv1, cW2, cb2, cg2, cbe2, cm2, cv2,
                     W2f, xyzb, bias2c, s1arr);
  hipLaunchKernelGGL(k0_neighbors, dim3(512), dim3(256), 0, stream,
                     seed_xyz, vp_rot, idx_arr, gxyz4);
  hipLaunchKernelGGL(k1_f1, dim3(512), dim3(256), 0, stream,
                     seed_feat, cW1, s1arr, F1);
  hipLaunchKernelGGL(k2_layer2, dim3(2048), dim3(256), 0, stream,
                     idx_arr, gxyz4, F1, W2f, xyzb, bias2c, cat);
  hipLaunchKernelGGL(k3_trans, dim3(128), dim3(256), 0, stream,
                     seed_feat, trans_W, trans_b, seedt);
  hipLaunchKernelGGL(k3_fuse, dim3(128), dim3(256), 0, stream,
                     cat, fuse_W, fuse_b, fusedb);
  hipLaunchKernelGGL(k3_gate, dim3(128), dim3(256), 0, stream,
                     seedt, gate_W, gate_b, fusedb, (float*)d_out);
}

// Round 15
// 298.495 us; speedup vs baseline: 1.5529x; 1.0422x over previous
//
#include <hip/hip_runtime.h>
#include <math.h>

typedef __attribute__((ext_vector_type(8))) short short8;
typedef __attribute__((ext_vector_type(4))) float f32x4;

__device__ __forceinline__ unsigned short bf16_bits(float f) {
  unsigned u = __float_as_uint(f);
  u += 0x7fffu + ((u >> 16) & 1u);
  return (unsigned short)(u >> 16);
}

// ---------------------------------------------------------------- K0b: prep
// Fold BN scales; W2 -> bf16 in MFMA-FRAGMENT ORDER:
// W2f[s][ks][t][l] (16B) = W2'[o=t*16+(l&15)][k=ks*32+(l>>4)*8 .. +8)
__global__ __launch_bounds__(256) void k0b_prep(
    const float* __restrict__ W1, const float* __restrict__ b1, const float* __restrict__ g1,
    const float* __restrict__ be1, const float* __restrict__ m1, const float* __restrict__ v1,
    const float* __restrict__ W2, const float* __restrict__ b2, const float* __restrict__ g2,
    const float* __restrict__ be2, const float* __restrict__ m2, const float* __restrict__ v2,
    unsigned short* __restrict__ W2f, float4* __restrict__ xyzb,
    float* __restrict__ bias2c, float* __restrict__ s1arr) {
  const int so = blockIdx.x;      // s*256 + o
  const int j  = threadIdx.x;     // k
  const int s = so >> 8, o = so & 255;
  const float s2 = rsqrtf(v2[so] + 1e-5f) * g2[so];
  const int t = o >> 4, r = o & 15;
  const int ks = j >> 5, hi = (j >> 3) & 3, i = j & 7;
  const int l = hi * 16 + r;
  W2f[(size_t)s * 65536 + (size_t)((ks * 16 + t) << 9) + l * 8 + i] =
      bf16_bits(W2[(size_t)so * 256 + j] * s2);
  if (j == 0) {
    const float s1 = rsqrtf(v1[so] + 1e-5f) * g1[so];
    const float* wr = W1 + (size_t)so * 515;
    xyzb[so] = make_float4(wr[0] * s1, wr[1] * s1, wr[2] * s1,
                           (b1[so] - m1[so]) * s1 + be1[so]);
    bias2c[so] = (b2[so] - m2[so]) * s2 + be2[so];
    s1arr[so] = s1;
  }
}

// ------------------------------------------------------------ K0: neighbors
__global__ __launch_bounds__(256) void k0_neighbors(
    const float* __restrict__ xyz, const float* __restrict__ rot,
    int* __restrict__ idx_arr, float4* __restrict__ gxyz4) {
  const int wid = threadIdx.x >> 6, lane = threadIdx.x & 63;
  const int gw = blockIdx.x * 4 + wid;
  const int b = gw >> 10, m = gw & 1023;
  const float* pm = xyz + (size_t)(b * 1024 + m) * 3;
  const float cx = pm[0], cy = pm[1], cz = pm[2];
  const float* pr = rot + (size_t)(b * 1024 + m) * 9;
  float R[9];
#pragma unroll
  for (int i = 0; i < 9; ++i) R[i] = pr[i];
  const float radf[4] = {0.0125f, 0.025f, 0.0375f, 0.05f};
  const float rad2[4] = {(float)(0.0125 * 0.0125), (float)(0.025 * 0.025),
                         (float)(0.0375 * 0.0375), (float)(0.05 * 0.05)};
  int cnt[4] = {0, 0, 0, 0};
  int firstn[4] = {0, 0, 0, 0};
  float f0x[4] = {0, 0, 0, 0}, f0y[4] = {0, 0, 0, 0}, f0z[4] = {0, 0, 0, 0};
  for (int n0 = 0; n0 < 1024; n0 += 64) {
    const int n = n0 + lane;
    const float* pn = xyz + (size_t)(b * 1024 + n) * 3;
    const float dx = pn[0] - cx, dy = pn[1] - cy, dz = pn[2] - cz;
    const float l0 = dx * R[0] + dy * R[3] + dz * R[6];
    const float l1 = dx * R[1] + dy * R[4] + dz * R[7];
    const float l2 = dx * R[2] + dy * R[5] + dz * R[8];
    const float d2 = l1 * l1 + l2 * l2;
    const bool hok = (l0 > -0.02f) && (l0 < 0.04f);
#pragma unroll
    for (int s = 0; s < 4; ++s) {
      if (cnt[s] >= 16) continue;                       // wave-uniform
      const bool p = hok && (d2 < rad2[s]);
      const unsigned long long bal = __ballot(p);
      if (bal == 0ull) continue;                        // wave-uniform
      if (cnt[s] == 0) {
        const int src = __builtin_ctzll(bal);
        firstn[s] = n0 + src;
        f0x[s] = __shfl(l0, src);
        f0y[s] = __shfl(l1, src);
        f0z[s] = __shfl(l2, src);
      }
      const int rank = __popcll(bal & ((1ull << lane) - 1ull));
      const int slot = cnt[s] + rank;
      if (p && slot < 16) {
        const size_t base = ((size_t)((s * 2 + b) * 1024 + m)) * 16 + slot;
        idx_arr[base] = n;
        gxyz4[base] = make_float4(l0 / radf[s], l1 / radf[s], l2 / radf[s], 0.f);
      }
      cnt[s] = min(cnt[s] + (int)__popcll(bal), 16);
    }
  }
#pragma unroll
  for (int s = 0; s < 4; ++s) {
    if (lane < 16 && lane >= cnt[s]) {
      const size_t base = ((size_t)((s * 2 + b) * 1024 + m)) * 16 + lane;
      idx_arr[base] = firstn[s];
      gxyz4[base] = make_float4(f0x[s] / radf[s], f0y[s] / radf[s], f0z[s] / radf[s], 0.f);
    }
  }
}

// ---------------------------------------------------------------- K1: F1 GEMM
__global__ __launch_bounds__(256) void k1_f1(
    const float* __restrict__ feats, const float* __restrict__ W1,
    const float* __restrict__ s1arr, float* __restrict__ F1) {
  __shared__ float At[16][68];
  __shared__ float Bt[16][68];
  const int bid = blockIdx.x;
  const int ogt = bid & 15, nt = (bid >> 4) & 15, b = bid >> 8;
  const int og0 = ogt * 64, n0 = nt * 64;
  const int tx = threadIdx.x & 15, ty = threadIdx.x >> 4;
  float acc[4][4] = {};
  for (int c0 = 0; c0 < 512; c0 += 16) {
#pragma unroll
    for (int it = 0; it < 4; ++it) {
      const int t = threadIdx.x + it * 256;
      { const int cc = t >> 6, nn = t & 63;
        At[cc][nn] = feats[((size_t)(b * 512 + c0 + cc)) * 1024 + n0 + nn]; }
      { const int cc = t & 15, nn = t >> 4;            // coalesced along c
        const int og = og0 + nn;
        Bt[cc][nn] = W1[(size_t)og * 515 + 3 + c0 + cc] * s1arr[og]; }
    }
    __syncthreads();
#pragma unroll
    for (int cc = 0; cc < 16; ++cc) {
      const float4 a = *(const float4*)&At[cc][ty * 4];
      const float4 bv = *(const float4*)&Bt[cc][tx * 4];
      const float av[4] = {a.x, a.y, a.z, a.w};
      const float bw[4] = {bv.x, bv.y, bv.z, bv.w};
#pragma unroll
      for (int i = 0; i < 4; ++i)
#pragma unroll
        for (int j = 0; j < 4; ++j) acc[i][j] = fmaf(av[i], bw[j], acc[i][j]);
    }
    __syncthreads();
  }
  const int s = og0 >> 8;
  const int obase = (og0 & 255) + tx * 4;
#pragma unroll
  for (int i = 0; i < 4; ++i) {
    const int n = n0 + ty * 4 + i;
    float4 w;
    w.x = acc[i][0]; w.y = acc[i][1]; w.z = acc[i][2]; w.w = acc[i][3];
    *(float4*)&F1[(((size_t)(s * 2 + b)) * 1024 + n) * 256 + obase] = w;
  }
}

// ------------------------------------------------- K2: finalize L1 + L2 MFMA + max
// v4: no LDS, no barriers. W2f fragment-order => per-lane 16B loads are
// coalesced (wave reads contiguous 1KB per t) and L2/L1-hot. Occupancy
// uncapped (no LDS) -> TLP hides load latency.
__global__ __launch_bounds__(256) void k2_layer2(
    const int* __restrict__ idx_arr, const float4* __restrict__ gxyz4,
    const float* __restrict__ F1, const unsigned short* __restrict__ W2f,
    const float4* __restrict__ xyzb, const float* __restrict__ bias2c,
    float* __restrict__ cat) {
  const int wid = threadIdx.x >> 6, lane = threadIdx.x & 63;
  const int bid = blockIdx.x;
  const int mg = bid & 255, b = (bid >> 8) & 1, s = bid >> 9;
  const int m = mg * 4 + wid;
  const int r = lane & 15, hi = lane >> 4;
  const size_t sb = (size_t)((s * 2 + b) * 1024 + m) * 16 + r;
  const int n = idx_arr[sb];
  const float4 g = gxyz4[sb];
  const float* __restrict__ f1row = F1 + ((size_t)((s * 2 + b) * 1024) + n) * 256;
  const unsigned short* __restrict__ w2f = W2f + (size_t)s * 65536;
  const float4* __restrict__ xbs = xyzb + s * 256;

  // F1 gathers up-front (16 loads in flight)
  float4 pf[16];
#pragma unroll
  for (int ks = 0; ks < 8; ++ks) {
    const int j0 = ks * 32 + hi * 8;
    pf[ks * 2]     = *(const float4*)(f1row + j0);
    pf[ks * 2 + 1] = *(const float4*)(f1row + j0 + 4);
  }

  f32x4 acc[16];
#pragma unroll
  for (int t = 0; t < 16; ++t) { acc[t][0] = 0.f; acc[t][1] = 0.f; acc[t][2] = 0.f; acc[t][3] = 0.f; }

#pragma unroll
  for (int ks = 0; ks < 8; ++ks) {
    const unsigned short* wk = w2f + ((size_t)(ks * 16) << 9) + lane * 8;
    // 16 coalesced B-fragment loads (1KB/wave each, L2/L1-hot)
    short8 bf[16];
#pragma unroll
    for (int t = 0; t < 16; ++t)
      bf[t] = *(const short8*)(wk + ((size_t)t << 9));
    const int j0 = ks * 32 + hi * 8;
    const float4 fa = pf[ks * 2], fb = pf[ks * 2 + 1];
    const float fv[8] = {fa.x, fa.y, fa.z, fa.w, fb.x, fb.y, fb.z, fb.w};
    short8 af;
#pragma unroll
    for (int i = 0; i < 8; ++i) {
      const float4 xb = xbs[j0 + i];
      float v = fv[i] + xb.w;
      v = fmaf(g.x, xb.x, v);
      v = fmaf(g.y, xb.y, v);
      v = fmaf(g.z, xb.z, v);
      v = fmaxf(v, 0.f);
      af[i] = (short)bf16_bits(v);
    }
#pragma unroll
    for (int t = 0; t < 16; ++t)
      acc[t] = __builtin_amdgcn_mfma_f32_16x16x32_bf16(af, bf[t], acc[t], 0, 0, 0);
  }

  float* __restrict__ catrow = cat + ((size_t)(b * 1024 + m)) * 1024 + s * 256;
#pragma unroll
  for (int t = 0; t < 16; ++t) {
    const float bc = bias2c[s * 256 + t * 16 + r];
    float mv = fmaxf(acc[t][0] + bc, 0.f);
    mv = fmaxf(mv, fmaxf(acc[t][1] + bc, 0.f));
    mv = fmaxf(mv, fmaxf(acc[t][2] + bc, 0.f));
    mv = fmaxf(mv, fmaxf(acc[t][3] + bc, 0.f));
    mv = fmaxf(mv, __shfl_xor(mv, 16));
    mv = fmaxf(mv, __shfl_xor(mv, 32));
    if (hi == 0) catrow[t * 16 + r] = mv;
  }
}

// ---- K3 common tiling v2: 32og x 64m per block (2x grid vs before) ----
// tx = t&7 -> og = og0 + tx*4 + j; ty = t>>3 -> m = m0 + ty*2 + i.

// ------------------------------------------------------------ K3a: trans GEMM
__global__ __launch_bounds__(256) void k3_trans(
    const float* __restrict__ feats, const float* __restrict__ W,
    const float* __restrict__ bias, float* __restrict__ outp) {
  __shared__ float At[16][68];
  __shared__ float Bt[16][36];
  const int bid = blockIdx.x;
  const int ot = bid & 7, nt = (bid >> 3) & 15, b = bid >> 7;
  const int og0 = ot * 32, m0 = nt * 64;
  const int tx = threadIdx.x & 7, ty = threadIdx.x >> 3;
  float acc[2][4] = {};
  for (int c0 = 0; c0 < 512; c0 += 16) {
#pragma unroll
    for (int it = 0; it < 4; ++it) {
      const int t = threadIdx.x + it * 256;
      const int cc = t >> 6, nn = t & 63;
      At[cc][nn] = feats[((size_t)(b * 512 + c0 + cc)) * 1024 + m0 + nn];
    }
#pragma unroll
    for (int it = 0; it < 2; ++it) {
      const int t = threadIdx.x + it * 256;
      const int cc = t & 15, nn = t >> 4;              // coalesced along c
      Bt[cc][nn] = W[(size_t)(og0 + nn) * 512 + c0 + cc];
    }
    __syncthreads();
#pragma unroll
    for (int cc = 0; cc < 16; ++cc) {
      const float2 a = *(const float2*)&At[cc][ty * 2];
      const float4 bv = *(const float4*)&Bt[cc][tx * 4];
      const float av[2] = {a.x, a.y};
      const float bw[4] = {bv.x, bv.y, bv.z, bv.w};
#pragma unroll
      for (int i = 0; i < 2; ++i)
#pragma unroll
        for (int j = 0; j < 4; ++j) acc[i][j] = fmaf(av[i], bw[j], acc[i][j]);
    }
    __syncthreads();
  }
#pragma unroll
  for (int j = 0; j < 4; ++j) {
    const int og = og0 + tx * 4 + j;
    const float bb = bias[og];
#pragma unroll
    for (int i = 0; i < 2; ++i)
      outp[((size_t)(b * 256 + og)) * 1024 + m0 + ty * 2 + i] = acc[i][j] + bb;
  }
}

// ------------------------------------------------------------- K3b: fuse GEMM
__global__ __launch_bounds__(256) void k3_fuse(
    const float* __restrict__ cat, const float* __restrict__ W,
    const float* __restrict__ bias, float* __restrict__ outp) {
  __shared__ float At[16][68];
  __shared__ float Bt[16][36];
  const int bid = blockIdx.x;
  const int ot = bid & 7, nt = (bid >> 3) & 15, b = bid >> 7;
  const int og0 = ot * 32, m0 = nt * 64;
  const int tx = threadIdx.x & 7, ty = threadIdx.x >> 3;
  float acc[2][4] = {};
  for (int c0 = 0; c0 < 1024; c0 += 16) {
#pragma unroll
    for (int it = 0; it < 4; ++it) {
      const int t = threadIdx.x + it * 256;
      const int mm = t >> 4, cj = t & 15;              // transpose-stage A (coalesced read)
      At[cj][mm] = cat[((size_t)(b * 1024 + m0 + mm)) * 1024 + c0 + cj];
    }
#pragma unroll
    for (int it = 0; it < 2; ++it) {
      const int t = threadIdx.x + it * 256;
      const int cc = t & 15, nn = t >> 4;              // coalesced along c
      Bt[cc][nn] = W[(size_t)(og0 + nn) * 1024 + c0 + cc];
    }
    __syncthreads();
#pragma unroll
    for (int cc = 0; cc < 16; ++cc) {
      const float2 a = *(const float2*)&At[cc][ty * 2];
      const float4 bv = *(const float4*)&Bt[cc][tx * 4];
      const float av[2] = {a.x, a.y};
      const float bw[4] = {bv.x, bv.y, bv.z, bv.w};
#pragma unroll
      for (int i = 0; i < 2; ++i)
#pragma unroll
        for (int j = 0; j < 4; ++j) acc[i][j] = fmaf(av[i], bw[j], acc[i][j]);
    }
    __syncthreads();
  }
#pragma unroll
  for (int j = 0; j < 4; ++j) {
    const int og = og0 + tx * 4 + j;
    const float bb = bias[og];
#pragma unroll
    for (int i = 0; i < 2; ++i)
      outp[((size_t)(b * 256 + og)) * 1024 + m0 + ty * 2 + i] = acc[i][j] + bb;
  }
}

// --------------------------------------------- K3c: gate GEMM + final combine
__global__ __launch_bounds__(256) void k3_gate(
    const float* __restrict__ seedt, const float* __restrict__ W,
    const float* __restrict__ bias, const float* __restrict__ fused,
    float* __restrict__ outp) {
  __shared__ float At[16][68];
  __shared__ float Bt[16][36];
  const int bid = blockIdx.x;
  const int ot = bid & 7, nt = (bid >> 3) & 15, b = bid >> 7;
  const int og0 = ot * 32, m0 = nt * 64;
  const int tx = threadIdx.x & 7, ty = threadIdx.x >> 3;
  float acc[2][4] = {};
  for (int c0 = 0; c0 < 256; c0 += 16) {
#pragma unroll
    for (int it = 0; it < 4; ++it) {
      const int t = threadIdx.x + it * 256;
      const int cc = t >> 6, nn = t & 63;
      At[cc][nn] = seedt[((size_t)(b * 256 + c0 + cc)) * 1024 + m0 + nn];
    }
#pragma unroll
    for (int it = 0; it < 2; ++it) {
      const int t = threadIdx.x + it * 256;
      const int cc = t & 15, nn = t >> 4;              // coalesced along c
      Bt[cc][nn] = W[(size_t)(og0 + nn) * 256 + c0 + cc];
    }
    __syncthreads();
#pragma unroll
    for (int cc = 0; cc < 16; ++cc) {
      const float2 a = *(const float2*)&At[cc][ty * 2];
      const float4 bv = *(const float4*)&Bt[cc][tx * 4];
      const float av[2] = {a.x, a.y};
      const float bw[4] = {bv.x, bv.y, bv.z, bv.w};
#pragma unroll
      for (int i = 0; i < 2; ++i)
#pragma unroll
        for (int j = 0; j < 4; ++j) acc[i][j] = fmaf(av[i], bw[j], acc[i][j]);
    }
    __syncthreads();
  }
#pragma unroll
  for (int j = 0; j < 4; ++j) {
    const int og = og0 + tx * 4 + j;
    const float gb = bias[og];
#pragma unroll
    for (int i = 0; i < 2; ++i) {
      const size_t oidx = ((size_t)(b * 256 + og)) * 1024 + m0 + ty * 2 + i;
      const float a = acc[i][j] + gb;
      const float gv = 1.f / (1.f + expf(-a));
      outp[oidx] = fused[oidx] + gv * seedt[oidx];
    }
  }
}

// ---------------------------------------------------------------------------
extern "C" void kernel_launch(void* const* d_in, const int* in_sizes, int n_in,
                              void* d_out, int out_size, void* d_ws, size_t ws_size,
                              hipStream_t stream) {
  (void)in_sizes; (void)n_in; (void)out_size; (void)ws_size;
  const float* seed_xyz  = (const float*)d_in[0];
  const float* seed_feat = (const float*)d_in[1];
  const float* vp_rot    = (const float*)d_in[2];
  const float* cW1  = (const float*)d_in[3];
  const float* cb1  = (const float*)d_in[4];
  const float* cg1  = (const float*)d_in[5];
  const float* cbe1 = (const float*)d_in[6];
  const float* cm1  = (const float*)d_in[7];
  const float* cv1  = (const float*)d_in[8];
  const float* cW2  = (const float*)d_in[9];
  const float* cb2  = (const float*)d_in[10];
  const float* cg2  = (const float*)d_in[11];
  const float* cbe2 = (const float*)d_in[12];
  const float* cm2  = (const float*)d_in[13];
  const float* cv2  = (const float*)d_in[14];
  const float* fuse_W  = (const float*)d_in[15];
  const float* fuse_b  = (const float*)d_in[16];
  const float* gate_W  = (const float*)d_in[17];
  const float* gate_b  = (const float*)d_in[18];
  const float* trans_W = (const float*)d_in[19];
  const float* trans_b = (const float*)d_in[20];

  char* ws = (char*)d_ws;
  float4* gxyz4        = (float4*)(ws + 0);          //  2 MB
  float4* xyzb         = (float4*)(ws + 2097152);    // 16 KB
  float* F1            = (float*)(ws + 2113536);     //  8 MB
  float* cat           = (float*)(ws + 10502144);    //  8 MB
  float* seedt         = (float*)(ws + 18890752);    //  2 MB
  float* fusedb        = (float*)(ws + 20987904);    //  2 MB
  int* idx_arr         = (int*)(ws + 23085056);      // 512 KB
  unsigned short* W2f  = (unsigned short*)(ws + 23609344); // 512 KB (fragment order)
  float* bias2c        = (float*)(ws + 24133632);    //  4 KB
  float* s1arr         = (float*)(ws + 24137728);    //  4 KB

  hipLaunchKernelGGL(k0b_prep, dim3(1024), dim3(256), 0, stream,
                     cW1, cb1, cg1, cbe1, cm1, cv1, cW2, cb2, cg2, cbe2, cm2, cv2,
                     W2f, xyzb, bias2c, s1arr);
  hipLaunchKernelGGL(k0_neighbors, dim3(512), dim3(256), 0, stream,
                     seed_xyz, vp_rot, idx_arr, gxyz4);
  hipLaunchKernelGGL(k1_f1, dim3(512), dim3(256), 0, stream,
                     seed_feat, cW1, s1arr, F1);
  hipLaunchKernelGGL(k2_layer2, dim3(2048), dim3(256), 0, stream,
                     idx_arr, gxyz4, F1, W2f, xyzb, bias2c, cat);
  hipLaunchKernelGGL(k3_trans, dim3(256), dim3(256), 0, stream,
                     seed_feat, trans_W, trans_b, seedt);
  hipLaunchKernelGGL(k3_fuse, dim3(256), dim3(256), 0, stream,
                     cat, fuse_W, fuse_b, fusedb);
  hipLaunchKernelGGL(k3_gate, dim3(256), dim3(256), 0, stream,
                     seedt, gate_W, gate_b, fusedb, (float*)d_out);
}